// Round 1
// baseline (9070.382 us; speedup 1.0000x reference)
//
#include <hip/hip_runtime.h>
#include <hip/hip_bf16.h>
#include <stdint.h>

// AutoRegressive LSTM (B=1024, T=256, I=64, U=1024, S=64) on MI355X.
// fp16 MFMA (16x16x32), fp32 accum/state. One launch per LSTM step.
// All staged operands pre-tiled + XOR-swizzled so global_load_lds is a linear
// copy and ds_read_b128 is bank-uniform.

typedef _Float16 f16;
typedef _Float16 f16x8 __attribute__((ext_vector_type(8)));
typedef float f32x4 __attribute__((ext_vector_type(4)));

#define TILE_HALVES 8192   // one 128x64 (or 64-row variant) fp16 tile = 16KB
#define NKZ 17             // K=1088 in BK=64 chunks
#define NKH 16             // K=1024 for the dense head

// element index inside a [rows][64] fp16 tile, XOR-swizzled (16B granule)
__device__ __forceinline__ int swz(int r, int k) { return (r * 64 + k) ^ ((r & 7) << 3); }

// ---- staging: 16KB tile (8192 halves) via global_load_lds, 4 issues ----
__device__ __forceinline__ void stage8k(const f16* __restrict__ g, f16* l, int tid) {
  const int wave = tid >> 6, lane = tid & 63;
  const char* gp = (const char*)g;
  char* lp = (char*)l;
#pragma unroll
  for (int i = 0; i < 4; i++) {
    const int off = i * 4096 + wave * 1024;
    __builtin_amdgcn_global_load_lds(
        (const __attribute__((address_space(1))) unsigned int*)(gp + off + lane * 16),
        (__attribute__((address_space(3))) unsigned int*)(lp + off), 16, 0, 0);
  }
}
// 8KB tile (4096 halves), 2 issues
__device__ __forceinline__ void stage4k(const f16* __restrict__ g, f16* l, int tid) {
  const int wave = tid >> 6, lane = tid & 63;
  const char* gp = (const char*)g;
  char* lp = (char*)l;
#pragma unroll
  for (int i = 0; i < 2; i++) {
    const int off = i * 4096 + wave * 1024;
    __builtin_amdgcn_global_load_lds(
        (const __attribute__((address_space(1))) unsigned int*)(gp + off + lane * 16),
        (__attribute__((address_space(3))) unsigned int*)(lp + off), 16, 0, 0);
  }
}

__device__ __forceinline__ float sigf(float x) { return 1.0f / (1.0f + __expf(-x)); }
__device__ __forceinline__ float tanhfast(float x) { return 1.0f - 2.0f / (__expf(2.0f * x) + 1.0f); }

// ---------------- LSTM step kernel ----------------
// z = [x|h] @ [Wk;Wr] + b ; gate math ; update c (fp32, in place), write h (fp16, tiled)
// grid 256: mi = bid>>5 (8 row tiles of 128), ni = bid&31 (32 unit-groups of 32)
__global__ void __launch_bounds__(256) lstm_step(
    const f16* __restrict__ W16, const f16* __restrict__ Ax,
    const f16* __restrict__ hin, f16* __restrict__ hout,
    float* __restrict__ c32, const float* __restrict__ bperm) {
  const int tid = threadIdx.x;
  const int bid = blockIdx.x;
  const int mi = bid >> 5, ni = bid & 31;

  __shared__ __align__(16) f16 As[2][TILE_HALVES];
  __shared__ __align__(16) f16 Bs[2][TILE_HALVES];

  f32x4 acc[4][4];
#pragma unroll
  for (int a = 0; a < 4; a++)
#pragma unroll
    for (int q = 0; q < 4; q++) acc[a][q] = (f32x4){0.f, 0.f, 0.f, 0.f};

  const f16* Ablk0 = Ax + (size_t)mi * TILE_HALVES;                  // x or p tile (K rows 0..63)
  const f16* Ah = hin + (size_t)mi * 16 * TILE_HALVES;               // h tiles (K rows 64..1087)
  const f16* Wb = W16 + (size_t)ni * NKZ * TILE_HALVES;              // B panel for this unit-group

  stage8k(Ablk0, As[0], tid);
  stage8k(Wb, Bs[0], tid);

  const int w = tid >> 6, lane = tid & 63;
  const int rw = w >> 1, cw = w & 1, ln15 = lane & 15, ln4 = lane >> 4;

  for (int kk = 0; kk < NKZ; kk++) {
    __syncthreads();
    if (kk + 1 < NKZ) {
      stage8k(Ah + (size_t)kk * TILE_HALVES, As[(kk + 1) & 1], tid);
      stage8k(Wb + (size_t)(kk + 1) * TILE_HALVES, Bs[(kk + 1) & 1], tid);
    }
    const f16* Ab = As[kk & 1];
    const f16* Bb = Bs[kk & 1];
#pragma unroll
    for (int kc = 0; kc < 2; kc++) {
      const int kb = kc * 32 + ln4 * 8;
      f16x8 af[4], bf[4];
#pragma unroll
      for (int mf = 0; mf < 4; mf++) {
        const int r = 64 * rw + 16 * mf + ln15;
        af[mf] = *(const f16x8*)(Ab + swz(r, kb));
      }
#pragma unroll
      for (int nf = 0; nf < 4; nf++) {
        const int n = 64 * cw + 16 * nf + ln15;
        bf[nf] = *(const f16x8*)(Bb + swz(n, kb));
      }
#pragma unroll
      for (int mf = 0; mf < 4; mf++)
#pragma unroll
        for (int nf = 0; nf < 4; nf++)
          acc[mf][nf] = __builtin_amdgcn_mfma_f32_16x16x32_f16(af[mf], bf[nf], acc[mf][nf], 0, 0, 0);
    }
  }

  // ---- epilogue: gates -> c,h ----
  const int u_glob = 32 * ni + 16 * cw + ln15;   // unit owned by this lane
  const int kkh = u_glob >> 6, kh = u_glob & 63;
  f16* ob = hout + (size_t)(mi * 16 + kkh) * TILE_HALVES;
  const float bi0 = bperm[ni * 128 + 64 * cw + 0 + ln15];
  const float bi1 = bperm[ni * 128 + 64 * cw + 16 + ln15];
  const float bi2 = bperm[ni * 128 + 64 * cw + 32 + ln15];
  const float bi3 = bperm[ni * 128 + 64 * cw + 48 + ln15];
#pragma unroll
  for (int mf = 0; mf < 4; mf++) {
#pragma unroll
    for (int reg = 0; reg < 4; reg++) {
      const int r = 64 * rw + 16 * mf + 4 * ln4 + reg;
      const int brow = 128 * mi + r;
      const size_t cidx = (size_t)brow * 1024 + u_glob;
      const float zi = acc[mf][0][reg] + bi0;
      const float zf = acc[mf][1][reg] + bi1;
      const float zg = acc[mf][2][reg] + bi2;
      const float zo = acc[mf][3][reg] + bi3;
      const float co = c32[cidx];
      const float cn = sigf(zf) * co + sigf(zi) * tanhfast(zg);
      const float hn = sigf(zo) * tanhfast(cn);
      c32[cidx] = cn;
      ob[swz(r, kh)] = (f16)hn;
    }
  }
}

// ---------------- dense head: p = h @ Wd + bd ----------------
// grid 8 (mi). Writes p (fp16, A-tile layout for next step) + selected output cols.
__global__ void __launch_bounds__(256) head_kernel(
    const f16* __restrict__ Wd16, const f16* __restrict__ hin,
    f16* __restrict__ p16, const float* __restrict__ bd,
    const int* __restrict__ oidx, float* __restrict__ out,
    int n_idx, int s) {
  const int tid = threadIdx.x, mi = blockIdx.x;
  __shared__ __align__(16) f16 As[2][TILE_HALVES];
  __shared__ __align__(16) f16 Ws[2][4096];

  f32x4 acc[2][4];
#pragma unroll
  for (int a = 0; a < 2; a++)
#pragma unroll
    for (int q = 0; q < 4; q++) acc[a][q] = (f32x4){0.f, 0.f, 0.f, 0.f};

  const f16* Ah = hin + (size_t)mi * 16 * TILE_HALVES;
  stage8k(Ah, As[0], tid);
  stage4k(Wd16, Ws[0], tid);

  const int w = tid >> 6, lane = tid & 63, ln15 = lane & 15, ln4 = lane >> 4;

  for (int kk = 0; kk < NKH; kk++) {
    __syncthreads();
    if (kk + 1 < NKH) {
      stage8k(Ah + (size_t)(kk + 1) * TILE_HALVES, As[(kk + 1) & 1], tid);
      stage4k(Wd16 + (size_t)(kk + 1) * 4096, Ws[(kk + 1) & 1], tid);
    }
    const f16* Ab = As[kk & 1];
    const f16* Bb = Ws[kk & 1];
#pragma unroll
    for (int kc = 0; kc < 2; kc++) {
      const int kb = kc * 32 + ln4 * 8;
      f16x8 a0, a1, bf[4];
      { const int r = 32 * w + ln15;      a0 = *(const f16x8*)(Ab + swz(r, kb)); }
      { const int r = 32 * w + 16 + ln15; a1 = *(const f16x8*)(Ab + swz(r, kb)); }
#pragma unroll
      for (int nf = 0; nf < 4; nf++) {
        const int n = 16 * nf + ln15;
        bf[nf] = *(const f16x8*)(Bb + swz(n, kb));
      }
#pragma unroll
      for (int nf = 0; nf < 4; nf++) {
        acc[0][nf] = __builtin_amdgcn_mfma_f32_16x16x32_f16(a0, bf[nf], acc[0][nf], 0, 0, 0);
        acc[1][nf] = __builtin_amdgcn_mfma_f32_16x16x32_f16(a1, bf[nf], acc[1][nf], 0, 0, 0);
      }
    }
  }

#pragma unroll
  for (int mf = 0; mf < 2; mf++)
#pragma unroll
    for (int nf = 0; nf < 4; nf++) {
      const int col = 16 * nf + ln15;
      const float bdv = bd[col];
#pragma unroll
      for (int reg = 0; reg < 4; reg++) {
        const int r = 32 * w + 16 * mf + 4 * ln4 + reg;
        const float pv = acc[mf][nf][reg] + bdv;
        p16[(size_t)mi * TILE_HALVES + swz(r, col)] = (f16)pv;
        const int brow = 128 * mi + r;
        for (int oi = 0; oi < n_idx; oi++) {
          if (col == oidx[oi]) out[(size_t)brow * (64 * n_idx) + s * n_idx + oi] = pv;
        }
      }
    }
}

// ---------------- prep kernels (layout transforms, run each call) ----------------
// W16: per (ni,kk) a [n=128][k=64] fp16 tile, swizzled. n -> source col:
//   nf=n>>4, j=n&15, gate=nf&3, unit u=32*ni+16*(nf>>2)+j, col = gate*1024+u
__global__ void __launch_bounds__(256) prep_W(const float* __restrict__ Wk,
                                              const float* __restrict__ Wr,
                                              f16* __restrict__ W16) {
  const int blk = blockIdx.x;  // ni*17 + kk
  const int ni = blk / NKZ, kk = blk % NKZ;
  f16* ob = W16 + (size_t)blk * TILE_HALVES;
  for (int c = threadIdx.x; c < 1024; c += 256) {
    const int n = c >> 3, k0 = (c & 7) * 8;
    const int nf = n >> 4, j = n & 15;
    const int gate = nf & 3;
    const int u = 32 * ni + 16 * (nf >> 2) + j;
    const int col = gate * 1024 + u;
    f16x8 v;
#pragma unroll
    for (int e = 0; e < 8; e++) {
      const int kr = kk * 64 + k0 + e;
      const float val = (kr < 64) ? Wk[(size_t)kr * 4096 + col]
                                  : Wr[(size_t)(kr - 64) * 4096 + col];
      v[e] = (f16)val;
    }
    *(f16x8*)(ob + swz(n, k0)) = v;
  }
}

__global__ void __launch_bounds__(256) prep_Wd(const float* __restrict__ Wd, f16* __restrict__ Wd16) {
  const int kk = blockIdx.x;
  f16* ob = Wd16 + (size_t)kk * 4096;
  for (int c = threadIdx.x; c < 512; c += 256) {
    const int n = c >> 3, k0 = (c & 7) * 8;
    f16x8 v;
#pragma unroll
    for (int e = 0; e < 8; e++) {
      const int kr = kk * 64 + k0 + e;
      v[e] = (f16)Wd[(size_t)kr * 64 + n];
    }
    *(f16x8*)(ob + swz(n, k0)) = v;
  }
}

// X16: per (t,mi) a [r=128][k=64] fp16 tile of inputs[:,t,:], swizzled
__global__ void __launch_bounds__(256) prep_X(const float* __restrict__ inp, f16* __restrict__ X16) {
  const int blk = blockIdx.x;  // t*8 + mi
  const int t = blk >> 3, mi = blk & 7;
  f16* ob = X16 + (size_t)blk * TILE_HALVES;
  for (int c = threadIdx.x; c < 1024; c += 256) {
    const int r = c >> 3, k0 = (c & 7) * 8;
    const int b = 128 * mi + r;
    const float* src = inp + (size_t)b * 16384 + t * 64 + k0;
    const float4 x0 = *(const float4*)(src);
    const float4 x1 = *(const float4*)(src + 4);
    f16x8 v;
    v[0] = (f16)x0.x; v[1] = (f16)x0.y; v[2] = (f16)x0.z; v[3] = (f16)x0.w;
    v[4] = (f16)x1.x; v[5] = (f16)x1.y; v[6] = (f16)x1.z; v[7] = (f16)x1.w;
    *(f16x8*)(ob + swz(r, k0)) = v;
  }
}

__global__ void __launch_bounds__(256) prep_b(const float* __restrict__ b, float* __restrict__ bperm) {
  const int x = blockIdx.x * 256 + threadIdx.x;  // 4096
  const int ni = x >> 7, rem = x & 127, nf = rem >> 4, j = rem & 15;
  bperm[x] = b[(nf & 3) * 1024 + 32 * ni + 16 * (nf >> 2) + j];
}

// ---------------- host ----------------
extern "C" void kernel_launch(void* const* d_in, const int* in_sizes, int n_in,
                              void* d_out, int out_size, void* d_ws, size_t ws_size,
                              hipStream_t stream) {
  const float* inputs = (const float*)d_in[0];
  const float* Wk = (const float*)d_in[1];
  const float* Wr = (const float*)d_in[2];
  const float* bv = (const float*)d_in[3];
  const float* Wd = (const float*)d_in[4];
  const float* bd = (const float*)d_in[5];
  const int* oidx = (const int*)d_in[6];
  float* out = (float*)d_out;
  const int n_idx = out_size / (1024 * 64);
  if (n_idx < 1) return;

  char* ws = (char*)d_ws;
  const size_t OFF_W16 = 0;            // 544 tiles * 16KB = 8,912,896
  const size_t OFF_WD16 = 8912896;     // 16 * 8KB = 131,072
  const size_t OFF_BPERM = 9043968;    // 16,384
  const size_t OFF_C32 = 9060352;      // 4,194,304
  const size_t OFF_H0 = 13254656;      // 2,097,152
  const size_t OFF_H1 = 15351808;      // 2,097,152
  const size_t OFF_P16 = 17448960;     // 131,072
  const size_t OFF_X16 = 17580032;     // 33,554,432
  const size_t NEED = 51134464;
  if (ws_size < NEED) return;

  f16* W16 = (f16*)(ws + OFF_W16);
  f16* Wd16 = (f16*)(ws + OFF_WD16);
  float* bperm = (float*)(ws + OFF_BPERM);
  float* c32 = (float*)(ws + OFF_C32);
  f16* hb[2] = {(f16*)(ws + OFF_H0), (f16*)(ws + OFF_H1)};
  f16* p16 = (f16*)(ws + OFF_P16);
  f16* X16 = (f16*)(ws + OFF_X16);

  hipMemsetAsync(hb[0], 0, 2097152, stream);
  hipMemsetAsync(c32, 0, 4194304, stream);
  hipLaunchKernelGGL(prep_W, dim3(544), dim3(256), 0, stream, Wk, Wr, W16);
  hipLaunchKernelGGL(prep_Wd, dim3(16), dim3(256), 0, stream, Wd, Wd16);
  hipLaunchKernelGGL(prep_b, dim3(16), dim3(256), 0, stream, bv, bperm);
  hipLaunchKernelGGL(prep_X, dim3(2048), dim3(256), 0, stream, inputs, X16);

  // warmup: step t reads hb[t&1], writes hb[(t+1)&1]
  for (int t = 0; t < 256; t++) {
    hipLaunchKernelGGL(lstm_step, dim3(256), dim3(256), 0, stream,
                       (const f16*)W16, (const f16*)(X16 + (size_t)t * 8 * TILE_HALVES),
                       (const f16*)hb[t & 1], hb[(t + 1) & 1], c32, (const float*)bperm);
  }
  // decode: head(s) reads hb[s&1] (= state after 256+s steps), step feeds p back
  for (int s = 0; s < 64; s++) {
    hipLaunchKernelGGL(head_kernel, dim3(8), dim3(256), 0, stream,
                       (const f16*)Wd16, (const f16*)hb[s & 1], p16, bd, oidx, out, n_idx, s);
    if (s < 63) {
      hipLaunchKernelGGL(lstm_step, dim3(256), dim3(256), 0, stream,
                         (const f16*)W16, (const f16*)p16,
                         (const f16*)hb[s & 1], hb[(s + 1) & 1], c32, (const float*)bperm);
    }
  }
}

// Round 2
// 6900.879 us; speedup vs baseline: 1.3144x; 1.3144x over previous
//
#include <hip/hip_runtime.h>
#include <hip/hip_bf16.h>
#include <stdint.h>

// AutoRegressive LSTM (B=1024, T=256, I=64, U=1024, S=64) on MI355X.
// fp16 MFMA (16x16x32), fp32 accum/state. One launch per LSTM step.
// R1: 512-WG step kernel (64x128 tiles, 2 WG/CU) + XCD swizzle + latency-opt head.

typedef _Float16 f16;
typedef _Float16 f16x8 __attribute__((ext_vector_type(8)));
typedef float f32x4 __attribute__((ext_vector_type(4)));

#define TILE_HALVES 8192   // one 128x64 fp16 tile = 16KB
#define NKZ 17             // K=1088 in BK=64 chunks
#define NKH 16             // K=1024 for the dense head

// element index inside a [rows][64] fp16 tile, XOR-swizzled (16B granule)
__device__ __forceinline__ int swz(int r, int k) { return (r * 64 + k) ^ ((r & 7) << 3); }

// ---- staging via global_load_lds (linear copy; sources pre-swizzled) ----
__device__ __forceinline__ void stage8k(const f16* __restrict__ g, f16* l, int tid) {
  const int wave = tid >> 6, lane = tid & 63;
  const char* gp = (const char*)g;
  char* lp = (char*)l;
#pragma unroll
  for (int i = 0; i < 4; i++) {
    const int off = i * 4096 + wave * 1024;
    __builtin_amdgcn_global_load_lds(
        (const __attribute__((address_space(1))) unsigned int*)(gp + off + lane * 16),
        (__attribute__((address_space(3))) unsigned int*)(lp + off), 16, 0, 0);
  }
}
__device__ __forceinline__ void stage4k(const f16* __restrict__ g, f16* l, int tid) {
  const int wave = tid >> 6, lane = tid & 63;
  const char* gp = (const char*)g;
  char* lp = (char*)l;
#pragma unroll
  for (int i = 0; i < 2; i++) {
    const int off = i * 4096 + wave * 1024;
    __builtin_amdgcn_global_load_lds(
        (const __attribute__((address_space(1))) unsigned int*)(gp + off + lane * 16),
        (__attribute__((address_space(3))) unsigned int*)(lp + off), 16, 0, 0);
  }
}

__device__ __forceinline__ float sigf(float x) { return 1.0f / (1.0f + __expf(-x)); }
__device__ __forceinline__ float tanhfast(float x) { return 1.0f - 2.0f / (__expf(2.0f * x) + 1.0f); }

// ---------------- LSTM step kernel ----------------
// grid 512: xcd=bid&7, ni=4*xcd+((bid>>3)&3) (32 unit-groups of 32 units),
// mi=bid>>5 (16 row tiles of 64). Output tile 64 rows x 128 gate-cols.
// Same-ni WGs land on the same XCD -> B panels stay L2-local (4 panels/XCD).
__global__ void __launch_bounds__(256, 2) lstm_step(
    const f16* __restrict__ W16, const f16* __restrict__ Ax,
    const f16* __restrict__ hin, f16* __restrict__ hout,
    float* __restrict__ c32, const float* __restrict__ bperm) {
  const int tid = threadIdx.x;
  const int bid = blockIdx.x;
  const int xcd = bid & 7;
  const int ni = 4 * xcd + ((bid >> 3) & 3);  // 0..31
  const int mi = bid >> 5;                    // 0..15 (64-row tiles)

  __shared__ __align__(16) f16 As[2][4096];   // 64 x 64
  __shared__ __align__(16) f16 Bs[2][8192];   // 128 x 64

  f32x4 acc[2][4];
#pragma unroll
  for (int a = 0; a < 2; a++)
#pragma unroll
    for (int q = 0; q < 4; q++) acc[a][q] = (f32x4){0.f, 0.f, 0.f, 0.f};

  // A source: rows 64*mi..64*mi+63. x/p tile (mi>>1), half (mi&1); h tiles likewise.
  const f16* Ax0 = Ax + (size_t)(mi >> 1) * TILE_HALVES + (mi & 1) * 4096;
  const f16* Ah0 = hin + (size_t)(mi >> 1) * 16 * TILE_HALVES + (mi & 1) * 4096;
  const f16* Wb = W16 + (size_t)ni * NKZ * TILE_HALVES;

  stage4k(Ax0, As[0], tid);
  stage8k(Wb, Bs[0], tid);

  const int w = tid >> 6, lane = tid & 63;
  const int rw = w >> 1, cw = w & 1, ln15 = lane & 15, ln4 = lane >> 4;

  for (int kk = 0; kk < NKZ; kk++) {
    __syncthreads();
    if (kk + 1 < NKZ) {
      stage4k(Ah0 + (size_t)kk * TILE_HALVES, As[(kk + 1) & 1], tid);
      stage8k(Wb + (size_t)(kk + 1) * TILE_HALVES, Bs[(kk + 1) & 1], tid);
    }
    const f16* Ab = As[kk & 1];
    const f16* Bb = Bs[kk & 1];
#pragma unroll
    for (int kc = 0; kc < 2; kc++) {
      const int kb = kc * 32 + ln4 * 8;
      f16x8 af[2], bf[4];
#pragma unroll
      for (int mf = 0; mf < 2; mf++) {
        const int r = 32 * rw + 16 * mf + ln15;
        af[mf] = *(const f16x8*)(Ab + swz(r, kb));
      }
#pragma unroll
      for (int nf = 0; nf < 4; nf++) {
        const int n = 64 * cw + 16 * nf + ln15;
        bf[nf] = *(const f16x8*)(Bb + swz(n, kb));
      }
#pragma unroll
      for (int mf = 0; mf < 2; mf++)
#pragma unroll
        for (int nf = 0; nf < 4; nf++)
          acc[mf][nf] = __builtin_amdgcn_mfma_f32_16x16x32_f16(af[mf], bf[nf], acc[mf][nf], 0, 0, 0);
    }
  }

  // ---- epilogue: gates -> c,h ----
  const int u_glob = 32 * ni + 16 * cw + ln15;   // unit owned by this lane
  const int kkh = u_glob >> 6, kh = u_glob & 63;
  f16* ob = hout + ((size_t)(mi >> 1) * 16 + kkh) * TILE_HALVES;
  const float bi0 = bperm[ni * 128 + 64 * cw + 0 + ln15];
  const float bi1 = bperm[ni * 128 + 64 * cw + 16 + ln15];
  const float bi2 = bperm[ni * 128 + 64 * cw + 32 + ln15];
  const float bi3 = bperm[ni * 128 + 64 * cw + 48 + ln15];
#pragma unroll
  for (int mf = 0; mf < 2; mf++) {
#pragma unroll
    for (int reg = 0; reg < 4; reg++) {
      const int rl = 32 * rw + 16 * mf + 4 * ln4 + reg;
      const int brow = 64 * mi + rl;
      const int r128 = (mi & 1) * 64 + rl;
      const size_t cidx = (size_t)brow * 1024 + u_glob;
      const float zi = acc[mf][0][reg] + bi0;
      const float zf = acc[mf][1][reg] + bi1;
      const float zg = acc[mf][2][reg] + bi2;
      const float zo = acc[mf][3][reg] + bi3;
      const float co = c32[cidx];
      const float cn = sigf(zf) * co + sigf(zi) * tanhfast(zg);
      const float hn = sigf(zo) * tanhfast(cn);
      c32[cidx] = cn;
      ob[swz(r128, kh)] = (f16)hn;
    }
  }
}

// ---------------- dense head: p = h @ Wd + bd ----------------
// grid 16 (mi64), 4 waves. Wave w owns K-slice [256w,256w+256), loads A/B
// fragments DIRECT from global (L2-hot, no LDS staging, no barriers in K-loop),
// then 3-way LDS reduction; wave 0 does the epilogue.
__global__ void __launch_bounds__(256) head_kernel(
    const f16* __restrict__ Wd16, const f16* __restrict__ hin,
    f16* __restrict__ p16, const float* __restrict__ bd,
    const int* __restrict__ oidx, float* __restrict__ out,
    int n_idx, int s) {
  const int tid = threadIdx.x, mi = blockIdx.x;  // mi: 64-row tile, 0..15
  const int w = tid >> 6, lane = tid & 63, ln15 = lane & 15, ln4 = lane >> 4;

  __shared__ __align__(16) float red[3][16][292];

  f32x4 acc[4][4];
#pragma unroll
  for (int a = 0; a < 4; a++)
#pragma unroll
    for (int q = 0; q < 4; q++) acc[a][q] = (f32x4){0.f, 0.f, 0.f, 0.f};

  const size_t tile_base = (size_t)(mi >> 1) * 16;
  const int rhalf = (mi & 1) * 64;

#pragma unroll
  for (int kkl = 0; kkl < 4; kkl++) {
    const int kk_h = 4 * w + kkl;  // h K-chunk 0..15
    const f16* At = hin + (tile_base + kk_h) * TILE_HALVES;
    const f16* Bt = Wd16 + (size_t)kk_h * 4096;
#pragma unroll
    for (int kc = 0; kc < 2; kc++) {
      const int kb = kc * 32 + ln4 * 8;
      f16x8 af[4], bf[4];
#pragma unroll
      for (int mf = 0; mf < 4; mf++)
        af[mf] = *(const f16x8*)(At + swz(rhalf + 16 * mf + ln15, kb));
#pragma unroll
      for (int nf = 0; nf < 4; nf++)
        bf[nf] = *(const f16x8*)(Bt + swz(16 * nf + ln15, kb));
#pragma unroll
      for (int mf = 0; mf < 4; mf++)
#pragma unroll
        for (int nf = 0; nf < 4; nf++)
          acc[mf][nf] = __builtin_amdgcn_mfma_f32_16x16x32_f16(af[mf], bf[nf], acc[mf][nf], 0, 0, 0);
    }
  }

  const int lidx = lane * 4 + (lane >> 3) * 4;  // bank-spread f32x4 slot
  if (w > 0) {
#pragma unroll
    for (int mf = 0; mf < 4; mf++)
#pragma unroll
      for (int nf = 0; nf < 4; nf++)
        *(f32x4*)&red[w - 1][mf * 4 + nf][lidx] = acc[mf][nf];
  }
  __syncthreads();
  if (w == 0) {
#pragma unroll
    for (int mf = 0; mf < 4; mf++)
#pragma unroll
      for (int nf = 0; nf < 4; nf++) {
        const int slot = mf * 4 + nf;
        acc[mf][nf] += *(const f32x4*)&red[0][slot][lidx];
        acc[mf][nf] += *(const f32x4*)&red[1][slot][lidx];
        acc[mf][nf] += *(const f32x4*)&red[2][slot][lidx];
      }
#pragma unroll
    for (int mf = 0; mf < 4; mf++)
#pragma unroll
      for (int nf = 0; nf < 4; nf++) {
        const int col = 16 * nf + ln15;
        const float bdv = bd[col];
#pragma unroll
        for (int reg = 0; reg < 4; reg++) {
          const int rl = 16 * mf + 4 * ln4 + reg;
          const float pv = acc[mf][nf][reg] + bdv;
          p16[(size_t)(mi >> 1) * TILE_HALVES + swz(rhalf + rl, col)] = (f16)pv;
          const int brow = 64 * mi + rl;
          for (int oi = 0; oi < n_idx; oi++) {
            if (col == oidx[oi]) out[(size_t)brow * (64 * n_idx) + s * n_idx + oi] = pv;
          }
        }
      }
  }
}

// ---------------- prep kernels (layout transforms, run each call) ----------------
// W16: per (ni,kk) a [n=128][k=64] fp16 tile, swizzled. n -> source col:
//   nf=n>>4, j=n&15, gate=nf&3, unit u=32*ni+16*(nf>>2)+j, col = gate*1024+u
__global__ void __launch_bounds__(256) prep_W(const float* __restrict__ Wk,
                                              const float* __restrict__ Wr,
                                              f16* __restrict__ W16) {
  const int blk = blockIdx.x;  // ni*17 + kk
  const int ni = blk / NKZ, kk = blk % NKZ;
  f16* ob = W16 + (size_t)blk * TILE_HALVES;
  for (int c = threadIdx.x; c < 1024; c += 256) {
    const int n = c >> 3, k0 = (c & 7) * 8;
    const int nf = n >> 4, j = n & 15;
    const int gate = nf & 3;
    const int u = 32 * ni + 16 * (nf >> 2) + j;
    const int col = gate * 1024 + u;
    f16x8 v;
#pragma unroll
    for (int e = 0; e < 8; e++) {
      const int kr = kk * 64 + k0 + e;
      const float val = (kr < 64) ? Wk[(size_t)kr * 4096 + col]
                                  : Wr[(size_t)(kr - 64) * 4096 + col];
      v[e] = (f16)val;
    }
    *(f16x8*)(ob + swz(n, k0)) = v;
  }
}

__global__ void __launch_bounds__(256) prep_Wd(const float* __restrict__ Wd, f16* __restrict__ Wd16) {
  const int kk = blockIdx.x;
  f16* ob = Wd16 + (size_t)kk * 4096;
  for (int c = threadIdx.x; c < 512; c += 256) {
    const int n = c >> 3, k0 = (c & 7) * 8;
    f16x8 v;
#pragma unroll
    for (int e = 0; e < 8; e++) {
      const int kr = kk * 64 + k0 + e;
      v[e] = (f16)Wd[(size_t)kr * 64 + n];
    }
    *(f16x8*)(ob + swz(n, k0)) = v;
  }
}

// X16: per (t,mi) a [r=128][k=64] fp16 tile of inputs[:,t,:], swizzled
__global__ void __launch_bounds__(256) prep_X(const float* __restrict__ inp, f16* __restrict__ X16) {
  const int blk = blockIdx.x;  // t*8 + mi
  const int t = blk >> 3, mi = blk & 7;
  f16* ob = X16 + (size_t)blk * TILE_HALVES;
  for (int c = threadIdx.x; c < 1024; c += 256) {
    const int r = c >> 3, k0 = (c & 7) * 8;
    const int b = 128 * mi + r;
    const float* src = inp + (size_t)b * 16384 + t * 64 + k0;
    const float4 x0 = *(const float4*)(src);
    const float4 x1 = *(const float4*)(src + 4);
    f16x8 v;
    v[0] = (f16)x0.x; v[1] = (f16)x0.y; v[2] = (f16)x0.z; v[3] = (f16)x0.w;
    v[4] = (f16)x1.x; v[5] = (f16)x1.y; v[6] = (f16)x1.z; v[7] = (f16)x1.w;
    *(f16x8*)(ob + swz(r, k0)) = v;
  }
}

__global__ void __launch_bounds__(256) prep_b(const float* __restrict__ b, float* __restrict__ bperm) {
  const int x = blockIdx.x * 256 + threadIdx.x;  // 4096
  const int ni = x >> 7, rem = x & 127, nf = rem >> 4, j = rem & 15;
  bperm[x] = b[(nf & 3) * 1024 + 32 * ni + 16 * (nf >> 2) + j];
}

// ---------------- host ----------------
extern "C" void kernel_launch(void* const* d_in, const int* in_sizes, int n_in,
                              void* d_out, int out_size, void* d_ws, size_t ws_size,
                              hipStream_t stream) {
  const float* inputs = (const float*)d_in[0];
  const float* Wk = (const float*)d_in[1];
  const float* Wr = (const float*)d_in[2];
  const float* bv = (const float*)d_in[3];
  const float* Wd = (const float*)d_in[4];
  const float* bd = (const float*)d_in[5];
  const int* oidx = (const int*)d_in[6];
  float* out = (float*)d_out;
  const int n_idx = out_size / (1024 * 64);
  if (n_idx < 1) return;

  char* ws = (char*)d_ws;
  const size_t OFF_W16 = 0;            // 544 tiles * 16KB = 8,912,896
  const size_t OFF_WD16 = 8912896;     // 16 * 8KB = 131,072
  const size_t OFF_BPERM = 9043968;    // 16,384
  const size_t OFF_C32 = 9060352;      // 4,194,304
  const size_t OFF_H0 = 13254656;      // 2,097,152
  const size_t OFF_H1 = 15351808;      // 2,097,152
  const size_t OFF_P16 = 17448960;     // 131,072
  const size_t OFF_X16 = 17580032;     // 33,554,432
  const size_t NEED = 51134464;
  if (ws_size < NEED) return;

  f16* W16 = (f16*)(ws + OFF_W16);
  f16* Wd16 = (f16*)(ws + OFF_WD16);
  float* bperm = (float*)(ws + OFF_BPERM);
  float* c32 = (float*)(ws + OFF_C32);
  f16* hb[2] = {(f16*)(ws + OFF_H0), (f16*)(ws + OFF_H1)};
  f16* p16 = (f16*)(ws + OFF_P16);
  f16* X16 = (f16*)(ws + OFF_X16);

  hipMemsetAsync(hb[0], 0, 2097152, stream);
  hipMemsetAsync(c32, 0, 4194304, stream);
  hipLaunchKernelGGL(prep_W, dim3(544), dim3(256), 0, stream, Wk, Wr, W16);
  hipLaunchKernelGGL(prep_Wd, dim3(16), dim3(256), 0, stream, Wd, Wd16);
  hipLaunchKernelGGL(prep_b, dim3(16), dim3(256), 0, stream, bv, bperm);
  hipLaunchKernelGGL(prep_X, dim3(2048), dim3(256), 0, stream, inputs, X16);

  // warmup: step t reads hb[t&1], writes hb[(t+1)&1]
  for (int t = 0; t < 256; t++) {
    hipLaunchKernelGGL(lstm_step, dim3(512), dim3(256), 0, stream,
                       (const f16*)W16, (const f16*)(X16 + (size_t)t * 8 * TILE_HALVES),
                       (const f16*)hb[t & 1], hb[(t + 1) & 1], c32, (const float*)bperm);
  }
  // decode: head(s) reads hb[s&1] (= state after 256+s steps), step feeds p back
  for (int s = 0; s < 64; s++) {
    hipLaunchKernelGGL(head_kernel, dim3(16), dim3(256), 0, stream,
                       (const f16*)Wd16, (const f16*)hb[s & 1], p16, bd, oidx, out, n_idx, s);
    if (s < 63) {
      hipLaunchKernelGGL(lstm_step, dim3(512), dim3(256), 0, stream,
                         (const f16*)W16, (const f16*)p16,
                         (const f16*)hb[s & 1], hb[(s + 1) & 1], c32, (const float*)bperm);
    }
  }
}

// Round 3
// 6234.528 us; speedup vs baseline: 1.4549x; 1.1069x over previous
//
#include <hip/hip_runtime.h>
#include <hip/hip_bf16.h>
#include <stdint.h>

// AutoRegressive LSTM (B=1024, T=256, I=64, U=1024, S=64) on MI355X.
// R2: counted-vmcnt 3-stage pipeline in the step kernel; decode head folded
// into the recurrence via W' = Wd@Wk + Wr (out cols via shuffle+atomic epilogue).

typedef _Float16 f16;
typedef _Float16 f16x8 __attribute__((ext_vector_type(8)));
typedef float f32x4 __attribute__((ext_vector_type(4)));

#define TILE_HALVES 8192   // one 128x64 fp16 tile = 16KB (two 64x64 halves of 4096)
#define NKZ 17             // warmup K=1088 in BK=64 chunks
#define NKD 16             // decode K=1024

// element index inside a [rows][64] fp16 tile, XOR-swizzled (16B granule)
__device__ __forceinline__ int swz(int r, int k) { return (r * 64 + k) ^ ((r & 7) << 3); }

// ---- staging via global_load_lds (linear copy; sources pre-swizzled) ----
__device__ __forceinline__ void stage8k(const f16* __restrict__ g, f16* l, int tid) {
  const int wave = tid >> 6, lane = tid & 63;
  const char* gp = (const char*)g;
  char* lp = (char*)l;
#pragma unroll
  for (int i = 0; i < 4; i++) {
    const int off = i * 4096 + wave * 1024;
    __builtin_amdgcn_global_load_lds(
        (const __attribute__((address_space(1))) unsigned int*)(gp + off + lane * 16),
        (__attribute__((address_space(3))) unsigned int*)(lp + off), 16, 0, 0);
  }
}
__device__ __forceinline__ void stage4k(const f16* __restrict__ g, f16* l, int tid) {
  const int wave = tid >> 6, lane = tid & 63;
  const char* gp = (const char*)g;
  char* lp = (char*)l;
#pragma unroll
  for (int i = 0; i < 2; i++) {
    const int off = i * 4096 + wave * 1024;
    __builtin_amdgcn_global_load_lds(
        (const __attribute__((address_space(1))) unsigned int*)(gp + off + lane * 16),
        (__attribute__((address_space(3))) unsigned int*)(lp + off), 16, 0, 0);
  }
}

__device__ __forceinline__ float sigf(float x) { return 1.0f / (1.0f + __expf(-x)); }
__device__ __forceinline__ float tanhfast(float x) { return 1.0f - 2.0f / (__expf(2.0f * x) + 1.0f); }

// ---------------- LSTM step kernel ----------------
// grid 512: xcd=bid&7, ni=4*xcd+((bid>>3)&3), mi=bid>>5 (16 row-tiles of 64).
// Output tile 64 rows x 128 gate-cols. 3-buffer LDS, counted vmcnt(6), one
// s_barrier per K-chunk. Epilogue: gates -> c,h (+ optional out-col atomics).
__global__ void __launch_bounds__(256, 2) lstm_step(
    const f16* __restrict__ Wp, const f16* __restrict__ Ax,
    const f16* __restrict__ hin, f16* __restrict__ hout,
    float* __restrict__ c32p, const float* __restrict__ bperm,
    const float* __restrict__ Wd, const int* __restrict__ oidx,
    float* __restrict__ outp, int n_idx, int nkz) {
  const int tid = threadIdx.x;
  const int bid = blockIdx.x;
  const int xcd = bid & 7;
  const int ni = 4 * xcd + ((bid >> 3) & 3);  // 0..31
  const int mi = bid >> 5;                    // 0..15

  __shared__ __align__(16) f16 As[3][4096];   // 64 x 64 each
  __shared__ __align__(16) f16 Bs[3][8192];   // 128 x 64 each

  const int has_x = (Ax != nullptr) ? 1 : 0;
  const f16* Ax0 = Ax + (size_t)(mi >> 1) * TILE_HALVES + (mi & 1) * 4096;
  const f16* Ah0 = hin + (size_t)(mi >> 1) * 16 * TILE_HALVES + (mi & 1) * 4096;
  const f16* Wb = Wp + (size_t)ni * nkz * TILE_HALVES;

  f32x4 acc[2][4];
#pragma unroll
  for (int a = 0; a < 2; a++)
#pragma unroll
    for (int q = 0; q < 4; q++) acc[a][q] = (f32x4){0.f, 0.f, 0.f, 0.f};

  // A-tile source for chunk kk
  auto atile = [&](int kk) -> const f16* {
    return (kk == 0 && has_x) ? Ax0 : (Ah0 + (size_t)(kk - has_x) * TILE_HALVES);
  };

  // prologue: stage chunks 0,1 into bufs 0,1  (6 issues/wave each)
  stage4k(atile(0), As[0], tid);
  stage8k(Wb, Bs[0], tid);
  stage4k(atile(1), As[1], tid);
  stage8k(Wb + TILE_HALVES, Bs[1], tid);

  const int w = tid >> 6, lane = tid & 63;
  const int rw = w >> 1, cw = w & 1, ln15 = lane & 15, ln4 = lane >> 4;

  int cur = 0;  // kk % 3
  for (int kk = 0; kk < nkz; kk++) {
    if (kk + 1 < nkz) {
      asm volatile("s_waitcnt vmcnt(6)" ::: "memory");   // chunk kk landed; kk+1 in flight
    } else {
      asm volatile("s_waitcnt vmcnt(0)" ::: "memory");
    }
    __builtin_amdgcn_s_barrier();
    if (kk + 2 < nkz) {
      int wr = cur + 2; if (wr >= 3) wr -= 3;            // (kk+2)%3, read at kk-1: safe
      stage4k(atile(kk + 2), As[wr], tid);
      stage8k(Wb + (size_t)(kk + 2) * TILE_HALVES, Bs[wr], tid);
    }
    const f16* Ab = As[cur];
    const f16* Bb = Bs[cur];
#pragma unroll
    for (int kc = 0; kc < 2; kc++) {
      const int kb = kc * 32 + ln4 * 8;
      f16x8 af[2], bf[4];
#pragma unroll
      for (int mf = 0; mf < 2; mf++) {
        const int r = 32 * rw + 16 * mf + ln15;
        af[mf] = *(const f16x8*)(Ab + swz(r, kb));
      }
#pragma unroll
      for (int nf = 0; nf < 4; nf++) {
        const int n = 64 * cw + 16 * nf + ln15;
        bf[nf] = *(const f16x8*)(Bb + swz(n, kb));
      }
      __builtin_amdgcn_s_setprio(1);
#pragma unroll
      for (int mf = 0; mf < 2; mf++)
#pragma unroll
        for (int nf = 0; nf < 4; nf++)
          acc[mf][nf] = __builtin_amdgcn_mfma_f32_16x16x32_f16(af[mf], bf[nf], acc[mf][nf], 0, 0, 0);
      __builtin_amdgcn_s_setprio(0);
    }
    cur = cur + 1; if (cur == 3) cur = 0;
  }

  // ---- epilogue: gates -> c,h ----
  const int u_glob = 32 * ni + 16 * cw + ln15;   // unit owned by this lane
  const int kkh = u_glob >> 6, kh = u_glob & 63;
  f16* ob = hout + ((size_t)(mi >> 1) * 16 + kkh) * TILE_HALVES;
  const float bi0 = bperm[ni * 128 + 64 * cw + 0 + ln15];
  const float bi1 = bperm[ni * 128 + 64 * cw + 16 + ln15];
  const float bi2 = bperm[ni * 128 + 64 * cw + 32 + ln15];
  const float bi3 = bperm[ni * 128 + 64 * cw + 48 + ln15];

  float* cp = c32p + ((size_t)bid * 256 + tid) * 8;     // lane-owned c, coalesced
  f32x4 cold0 = *(const f32x4*)(cp);
  f32x4 cold1 = *(const f32x4*)(cp + 4);

  float hv[2][4];
#pragma unroll
  for (int mf = 0; mf < 2; mf++) {
    f32x4 cn4;
#pragma unroll
    for (int reg = 0; reg < 4; reg++) {
      const int rl = 32 * rw + 16 * mf + 4 * ln4 + reg;
      const int r128 = (mi & 1) * 64 + rl;
      const float zi = acc[mf][0][reg] + bi0;
      const float zf = acc[mf][1][reg] + bi1;
      const float zg = acc[mf][2][reg] + bi2;
      const float zo = acc[mf][3][reg] + bi3;
      const float co = (mf == 0) ? cold0[reg] : cold1[reg];
      const float cn = sigf(zf) * co + sigf(zi) * tanhfast(zg);
      const float hn = sigf(zo) * tanhfast(cn);
      cn4[reg] = cn;
      hv[mf][reg] = hn;
      ob[swz(r128, kh)] = (f16)hn;
    }
    *(f32x4*)(cp + mf * 4) = cn4;
  }

  // ---- optional output columns: out[row, s, j] += sum_u h[row,u]*Wd[u,oidx[j]] ----
  if (outp != nullptr) {
    const int ostride = 64 * n_idx;
    for (int j = 0; j < n_idx; j++) {
      const float wdj = Wd[(size_t)u_glob * 64 + oidx[j]];
#pragma unroll
      for (int mf = 0; mf < 2; mf++)
#pragma unroll
        for (int reg = 0; reg < 4; reg++) {
          float v = hv[mf][reg] * wdj;
          v += __shfl_xor(v, 1);
          v += __shfl_xor(v, 2);
          v += __shfl_xor(v, 4);
          v += __shfl_xor(v, 8);
          if (ln15 == 0) {
            const int brow = 64 * mi + 32 * rw + 16 * mf + 4 * ln4 + reg;
            atomicAdd(&outp[(size_t)brow * ostride + j], v);
          }
        }
    }
  }
}

// ---------------- prep kernels ----------------
// W16: per (ni,kk) a [n=128][k=64] fp16 tile, swizzled. n -> source col:
//   nf=n>>4, j=n&15, gate=nf&3, unit u=32*ni+16*(nf>>2)+j, col = gate*1024+u
__global__ void __launch_bounds__(256) prep_W(const float* __restrict__ Wk,
                                              const float* __restrict__ Wr,
                                              f16* __restrict__ W16) {
  const int blk = blockIdx.x;  // ni*17 + kk
  const int ni = blk / NKZ, kk = blk % NKZ;
  f16* ob = W16 + (size_t)blk * TILE_HALVES;
  for (int c = threadIdx.x; c < 1024; c += 256) {
    const int n = c >> 3, k0 = (c & 7) * 8;
    const int nf = n >> 4, j = n & 15;
    const int gate = nf & 3;
    const int u = 32 * ni + 16 * (nf >> 2) + j;
    const int col = gate * 1024 + u;
    f16x8 v;
#pragma unroll
    for (int e = 0; e < 8; e++) {
      const int kr = kk * 64 + k0 + e;
      const float val = (kr < 64) ? Wk[(size_t)kr * 4096 + col]
                                  : Wr[(size_t)(kr - 64) * 4096 + col];
      v[e] = (f16)val;
    }
    *(f16x8*)(ob + swz(n, k0)) = v;
  }
}

// W' = Wd@Wk + Wr  (decode fused weights), 16 K-chunks per ni panel
__global__ void __launch_bounds__(256) prep_Wp(const float* __restrict__ Wk,
                                               const float* __restrict__ Wr,
                                               const float* __restrict__ Wd,
                                               f16* __restrict__ WP16) {
  const int blk = blockIdx.x;  // ni*16 + kk
  const int ni = blk / NKD, kk = blk % NKD;
  f16* ob = WP16 + (size_t)blk * TILE_HALVES;
  for (int c = threadIdx.x; c < 1024; c += 256) {
    const int n = c >> 3, k0 = (c & 7) * 8;
    const int nf = n >> 4, j = n & 15;
    const int gate = nf & 3;
    const int u = 32 * ni + 16 * (nf >> 2) + j;
    const int col = gate * 1024 + u;
    const int uh0 = kk * 64 + k0;
    float accv[8];
#pragma unroll
    for (int e = 0; e < 8; e++) accv[e] = Wr[(size_t)(uh0 + e) * 4096 + col];
#pragma unroll
    for (int i = 0; i < 64; i++) {
      const float wki = Wk[(size_t)i * 4096 + col];
#pragma unroll
      for (int e = 0; e < 8; e++)
        accv[e] += Wd[(size_t)(uh0 + e) * 64 + i] * wki;
    }
    f16x8 v;
#pragma unroll
    for (int e = 0; e < 8; e++) v[e] = (f16)accv[e];
    *(f16x8*)(ob + swz(n, k0)) = v;
  }
}

// X16: per (t,mi) a [r=128][k=64] fp16 tile of inputs[:,t,:], swizzled
__global__ void __launch_bounds__(256) prep_X(const float* __restrict__ inp, f16* __restrict__ X16) {
  const int blk = blockIdx.x;  // t*8 + mi
  const int t = blk >> 3, mi = blk & 7;
  f16* ob = X16 + (size_t)blk * TILE_HALVES;
  for (int c = threadIdx.x; c < 1024; c += 256) {
    const int r = c >> 3, k0 = (c & 7) * 8;
    const int b = 128 * mi + r;
    const float* src = inp + (size_t)b * 16384 + t * 64 + k0;
    const float4 x0 = *(const float4*)(src);
    const float4 x1 = *(const float4*)(src + 4);
    f16x8 v;
    v[0] = (f16)x0.x; v[1] = (f16)x0.y; v[2] = (f16)x0.z; v[3] = (f16)x0.w;
    v[4] = (f16)x1.x; v[5] = (f16)x1.y; v[6] = (f16)x1.z; v[7] = (f16)x1.w;
    *(f16x8*)(ob + swz(r, k0)) = v;
  }
}

__global__ void __launch_bounds__(256) prep_b(const float* __restrict__ b, float* __restrict__ bperm) {
  const int x = blockIdx.x * 256 + threadIdx.x;  // 4096
  const int ni = x >> 7, rem = x & 127, nf = rem >> 4, j = rem & 15;
  bperm[x] = b[(nf & 3) * 1024 + 32 * ni + 16 * (nf >> 2) + j];
}

// b' = b + bd@Wk, permuted
__global__ void __launch_bounds__(256) prep_b2(const float* __restrict__ b,
                                               const float* __restrict__ bd,
                                               const float* __restrict__ Wk,
                                               float* __restrict__ bperm2) {
  const int x = blockIdx.x * 256 + threadIdx.x;  // 4096
  const int ni = x >> 7, rem = x & 127, nf = rem >> 4, j = rem & 15;
  const int col = (nf & 3) * 1024 + 32 * ni + 16 * (nf >> 2) + j;
  float acc = b[col];
#pragma unroll
  for (int i = 0; i < 64; i++) acc += bd[i] * Wk[(size_t)i * 4096 + col];
  bperm2[x] = acc;
}

// out[row, s, j] initialized to bd[oidx[j]] (atomics then accumulate h@Wd cols)
__global__ void __launch_bounds__(256) out_init(float* __restrict__ out,
                                                const float* __restrict__ bd,
                                                const int* __restrict__ oidx,
                                                int n_idx, int total) {
  const int x = blockIdx.x * 256 + threadIdx.x;
  if (x < total) out[x] = bd[oidx[x % n_idx]];
}

// ---------------- host ----------------
extern "C" void kernel_launch(void* const* d_in, const int* in_sizes, int n_in,
                              void* d_out, int out_size, void* d_ws, size_t ws_size,
                              hipStream_t stream) {
  const float* inputs = (const float*)d_in[0];
  const float* Wk = (const float*)d_in[1];
  const float* Wr = (const float*)d_in[2];
  const float* bv = (const float*)d_in[3];
  const float* Wd = (const float*)d_in[4];
  const float* bd = (const float*)d_in[5];
  const int* oidx = (const int*)d_in[6];
  float* out = (float*)d_out;
  const int n_idx = out_size / (1024 * 64);
  if (n_idx < 1) return;

  char* ws = (char*)d_ws;
  const size_t OFF_W16 = 0;            // 544 * 16KB = 8,912,896
  const size_t OFF_BPERM = 8912896;    // 16,384
  const size_t OFF_C32 = 8929280;      // 4,194,304
  const size_t OFF_H0 = 13123584;      // 2,097,152
  const size_t OFF_H1 = 15220736;      // 2,097,152
  const size_t OFF_X16 = 17317888;     // 33,554,432 (reused mid-stream for W'/b')
  const size_t NEED = 50872320;
  if (ws_size < NEED) return;

  f16* W16 = (f16*)(ws + OFF_W16);
  float* bperm = (float*)(ws + OFF_BPERM);
  float* c32p = (float*)(ws + OFF_C32);
  f16* hb[2] = {(f16*)(ws + OFF_H0), (f16*)(ws + OFF_H1)};
  f16* X16 = (f16*)(ws + OFF_X16);
  // W' (8,388,608 B) + b' (16,384 B) live inside the X16 region, written after
  // warmup step 255 when the X tiles are dead (graph is stream-ordered).
  f16* WP16 = (f16*)(ws + OFF_X16);
  float* bperm2 = (float*)(ws + OFF_X16 + 8388608);

  hipMemsetAsync(hb[0], 0, 2097152, stream);
  hipMemsetAsync(c32p, 0, 4194304, stream);
  hipLaunchKernelGGL(prep_W, dim3(544), dim3(256), 0, stream, Wk, Wr, W16);
  hipLaunchKernelGGL(prep_b, dim3(16), dim3(256), 0, stream, bv, bperm);
  hipLaunchKernelGGL(prep_X, dim3(2048), dim3(256), 0, stream, inputs, X16);
  {
    const int total = 1024 * 64 * n_idx;
    hipLaunchKernelGGL(out_init, dim3((total + 255) / 256), dim3(256), 0, stream,
                       out, bd, oidx, n_idx, total);
  }

  // t = 0..318: warmup (t<256) uses W16 + x tile; decode uses W' (no x).
  // Kernel t also accumulates out[t-255] from its freshly computed h (t>=255).
  for (int t = 0; t < 319; ++t) {
    if (t == 256) {
      hipLaunchKernelGGL(prep_Wp, dim3(512), dim3(256), 0, stream, Wk, Wr, Wd, WP16);
      hipLaunchKernelGGL(prep_b2, dim3(16), dim3(256), 0, stream, bv, bd, Wk, bperm2);
    }
    const bool warm = (t < 256);
    const f16* W = warm ? W16 : WP16;
    const f16* Axp = warm ? (X16 + (size_t)t * 8 * TILE_HALVES) : nullptr;
    const float* bp = warm ? bperm : bperm2;
    float* op = (t >= 255) ? (out + (size_t)(t - 255) * n_idx) : nullptr;
    hipLaunchKernelGGL(lstm_step, dim3(512), dim3(256), 0, stream,
                       W, Axp, (const f16*)hb[t & 1], hb[(t + 1) & 1],
                       c32p, bp, Wd, oidx, op, n_idx, warm ? NKZ : NKD);
  }
}